// Round 4
// baseline (955.056 us; speedup 1.0000x reference)
//
#include <hip/hip_runtime.h>
#include <math.h>

typedef __attribute__((ext_vector_type(8))) short short8;
typedef __attribute__((ext_vector_type(4))) float f32x4;
typedef __attribute__((ext_vector_type(4))) unsigned int u32x4;

static __device__ __forceinline__ unsigned short f2bf(float f) {
    unsigned int u = __float_as_uint(f);
    unsigned int r = (u + 0x7FFFu + ((u >> 16) & 1u)) >> 16;
    return (unsigned short)r;
}
static __device__ __forceinline__ float blo(unsigned int u) { return __uint_as_float(u << 16); }
static __device__ __forceinline__ float bhi(unsigned int u) { return __uint_as_float(u & 0xFFFF0000u); }

// ---------------- graph build ----------------

__global__ void count_kernel(const int* __restrict__ ei, int* __restrict__ cnt, int E) {
    int e = blockIdx.x * 256 + threadIdx.x;
    if (e < E) atomicAdd(&cnt[ei[E + e]], 1);
}

__global__ void scanA_kernel(const int* __restrict__ cnt, float* __restrict__ dinv,
                             int* __restrict__ colptr, int* __restrict__ bsum, int n) {
    __shared__ int s[256];
    int b = blockIdx.x, t = threadIdx.x;
    int i = b * 512 + 2 * t;
    int c0 = (i     < n) ? cnt[i]     : 0;
    int c1 = (i + 1 < n) ? cnt[i + 1] : 0;
    if (i     < n) dinv[i]     = rsqrtf((float)(c0 + 1));
    if (i + 1 < n) dinv[i + 1] = rsqrtf((float)(c1 + 1));
    int v = c0 + c1;
    s[t] = v;
    __syncthreads();
    #pragma unroll
    for (int o = 1; o < 256; o <<= 1) {
        int x = (t >= o) ? s[t - o] : 0;
        __syncthreads();
        s[t] += x;
        __syncthreads();
    }
    int excl = s[t] - v;
    if (i     < n) colptr[i]     = excl;
    if (i + 1 < n) colptr[i + 1] = excl + c0;
    if (t == 255) bsum[b] = s[t];
}

__global__ void scanB_kernel(int* bsum, int nb) {
    __shared__ int s[256];
    int t = threadIdx.x;
    int v = (t < nb) ? bsum[t] : 0;
    s[t] = v;
    __syncthreads();
    #pragma unroll
    for (int o = 1; o < 256; o <<= 1) {
        int x = (t >= o) ? s[t - o] : 0;
        __syncthreads();
        s[t] += x;
        __syncthreads();
    }
    if (t < nb) bsum[t] = s[t] - v;
}

__global__ void scanC_kernel(int* __restrict__ colptr, const int* __restrict__ bsum,
                             int n, int E) {
    int b = blockIdx.x, t = threadIdx.x;
    int off = bsum[b];
    int i = b * 512 + 2 * t;
    if (i     < n) colptr[i]     += off;
    if (i + 1 < n) colptr[i + 1] += off;
    if (b == 0 && t == 0) colptr[n] = E;
}

__global__ void fill_kernel(const int* __restrict__ ei, const int* __restrict__ colptr,
                            int* __restrict__ fillc, int* __restrict__ eidx, int E) {
    int e = blockIdx.x * 256 + threadIdx.x;
    if (e < E) {
        int r = ei[e];
        int c = ei[E + e];
        int pos = colptr[c] + atomicAdd(&fillc[c], 1);
        eidx[pos] = r;
    }
}

// W1 [512][256] -> w1t [256][512] bf16 ; W2 [256][40] -> w2t [64][256] bf16 (pad 0)
__global__ void prep_w_kernel(const float* __restrict__ W1, const float* __restrict__ W2,
                              unsigned short* __restrict__ w1t, unsigned short* __restrict__ w2t) {
    int id = blockIdx.x * 256 + threadIdx.x;
    if (id < 512 * 256) {
        int k = id >> 8, n = id & 255;
        w1t[(size_t)n * 512 + k] = f2bf(W1[id]);
    } else {
        int id2 = id - 512 * 256;
        if (id2 < 64 * 256) {
            int n = id2 >> 8, k = id2 & 255;
            w2t[id2] = (n < 40) ? f2bf(W2[k * 40 + n]) : (unsigned short)0;
        }
    }
}

// ---------------- layer 1 GEMM ----------------
// xs = bf16((x @ W1) * dinv[row]). Tile 64(m) x 256(n), BK=32.
// A (x, fp32->bf16) staged in LDS (shared by all 4 waves, converted once).
// B (w1t) rows are wave-exclusive -> loaded DIRECTLY global->reg (L2-hot, 256KB),
// double-buffered in registers. No B LDS, no B staging instructions.
// x loads are non-temporal (read-once stream).

__global__ __launch_bounds__(256) void gemm1_kernel(const float* __restrict__ x,
                                                    const unsigned short* __restrict__ w1t,
                                                    const float* __restrict__ dinv,
                                                    unsigned short* __restrict__ xs, int M) {
    __shared__ unsigned short As[2][64 * 40];
    int t = threadIdx.x;
    int m0 = blockIdx.x * 64;
    int lane = t & 63, wv = t >> 6;
    int wn = wv * 64;
    int lm = lane & 15, q = lane >> 4;

    int ra = t >> 2, kc = (t & 3) * 8;
    int am = m0 + ra; if (am >= M) am = M - 1;
    const float* Ap = x + (size_t)am * 512 + kc;
    const unsigned short* Bq = w1t + (size_t)(wn + lm) * 512 + q * 8;

    f32x4 acc[4][4];
    f32x4 z = {0.f, 0.f, 0.f, 0.f};
    #pragma unroll
    for (int i = 0; i < 4; i++)
        #pragma unroll
        for (int j = 0; j < 4; j++) acc[i][j] = z;

    // prologue: stage A k=0 chunk; load B k=0 frags
    f32x4 a0 = __builtin_nontemporal_load((const f32x4*)(Ap + 0));
    f32x4 a1 = __builtin_nontemporal_load((const f32x4*)(Ap + 4));
    u32x4 bcur[4];
    #pragma unroll
    for (int j = 0; j < 4; j++) bcur[j] = *(const u32x4*)(Bq + j * 16 * 512);
    {
        u32x4 ap;
        ap.x = (unsigned int)f2bf(a0.x) | ((unsigned int)f2bf(a0.y) << 16);
        ap.y = (unsigned int)f2bf(a0.z) | ((unsigned int)f2bf(a0.w) << 16);
        ap.z = (unsigned int)f2bf(a1.x) | ((unsigned int)f2bf(a1.y) << 16);
        ap.w = (unsigned int)f2bf(a1.z) | ((unsigned int)f2bf(a1.w) << 16);
        *(u32x4*)&As[0][ra * 40 + kc] = ap;
    }
    __syncthreads();

    int buf = 0;
    for (int k0 = 0; k0 < 512; k0 += 32) {
        bool more = (k0 + 32) < 512;
        f32x4 na0, na1;
        u32x4 bnext[4];
        if (more) {
            na0 = __builtin_nontemporal_load((const f32x4*)(Ap + k0 + 32));
            na1 = __builtin_nontemporal_load((const f32x4*)(Ap + k0 + 36));
            #pragma unroll
            for (int j = 0; j < 4; j++)
                bnext[j] = *(const u32x4*)(Bq + j * 16 * 512 + k0 + 32);
        }
        short8 af[4];
        #pragma unroll
        for (int i = 0; i < 4; i++)
            af[i] = *(const short8*)&As[buf][(i * 16 + lm) * 40 + q * 8];
        #pragma unroll
        for (int i = 0; i < 4; i++)
            #pragma unroll
            for (int j = 0; j < 4; j++)
                acc[i][j] = __builtin_amdgcn_mfma_f32_16x16x32_bf16(af[i], *(const short8*)&bcur[j], acc[i][j], 0, 0, 0);
        if (more) {
            u32x4 ap;
            ap.x = (unsigned int)f2bf(na0.x) | ((unsigned int)f2bf(na0.y) << 16);
            ap.y = (unsigned int)f2bf(na0.z) | ((unsigned int)f2bf(na0.w) << 16);
            ap.z = (unsigned int)f2bf(na1.x) | ((unsigned int)f2bf(na1.y) << 16);
            ap.w = (unsigned int)f2bf(na1.z) | ((unsigned int)f2bf(na1.w) << 16);
            *(u32x4*)&As[buf ^ 1][ra * 40 + kc] = ap;
            __syncthreads();
            #pragma unroll
            for (int j = 0; j < 4; j++) bcur[j] = bnext[j];
        }
        buf ^= 1;
    }

    #pragma unroll
    for (int i = 0; i < 4; i++) {
        #pragma unroll
        for (int r = 0; r < 4; r++) {
            int m = m0 + i * 16 + q * 4 + r;
            if (m < M) {
                float d = dinv[m];
                #pragma unroll
                for (int j = 0; j < 4; j++) {
                    int n = wn + j * 16 + lm;
                    xs[(size_t)m * 256 + n] = f2bf(acc[i][j][r] * d);
                }
            }
        }
    }
}

// ---------------- layer 1 aggregate ----------------
// One wave per column. Lane l covers features (l&31)*8..+7 via uint4 (16B);
// lanes 0-31 even edges, 32-63 odd edges. 8 edges/iter in flight.
// h store is non-temporal (read much later by gemm2, streaming) to keep L2 for the gather.

__global__ __launch_bounds__(256) void spmm1_kernel(const unsigned short* __restrict__ xs,
                                                    const int* __restrict__ colptr,
                                                    const int* __restrict__ eidx,
                                                    const float* __restrict__ dinv,
                                                    const float* __restrict__ b1,
                                                    unsigned short* __restrict__ h, int Nn) {
    int wid = threadIdx.x >> 6, lane = threadIdx.x & 63;
    int c = blockIdx.x * 4 + wid;
    if (c >= Nn) return;
    int half = lane >> 5;
    int fl = lane & 31;
    const uint4* xb = (const uint4*)xs;

    uint4 sv = xb[(size_t)((unsigned)c * 32u + fl)];

    float a0 = 0.f, a1 = 0.f, a2 = 0.f, a3 = 0.f;
    float a4 = 0.f, a5 = 0.f, a6 = 0.f, a7 = 0.f;

    int j = colptr[c], jend = colptr[c + 1];

    for (; j + 8 <= jend; j += 8) {
        int r0 = eidx[j     + half];
        int r1 = eidx[j + 2 + half];
        int r2 = eidx[j + 4 + half];
        int r3 = eidx[j + 6 + half];
        uint4 v0 = xb[(size_t)((unsigned)r0 * 32u + fl)];
        uint4 v1 = xb[(size_t)((unsigned)r1 * 32u + fl)];
        uint4 v2 = xb[(size_t)((unsigned)r2 * 32u + fl)];
        uint4 v3 = xb[(size_t)((unsigned)r3 * 32u + fl)];
        a0 += (blo(v0.x) + blo(v1.x)) + (blo(v2.x) + blo(v3.x));
        a1 += (bhi(v0.x) + bhi(v1.x)) + (bhi(v2.x) + bhi(v3.x));
        a2 += (blo(v0.y) + blo(v1.y)) + (blo(v2.y) + blo(v3.y));
        a3 += (bhi(v0.y) + bhi(v1.y)) + (bhi(v2.y) + bhi(v3.y));
        a4 += (blo(v0.z) + blo(v1.z)) + (blo(v2.z) + blo(v3.z));
        a5 += (bhi(v0.z) + bhi(v1.z)) + (bhi(v2.z) + bhi(v3.z));
        a6 += (blo(v0.w) + blo(v1.w)) + (blo(v2.w) + blo(v3.w));
        a7 += (bhi(v0.w) + bhi(v1.w)) + (bhi(v2.w) + bhi(v3.w));
    }
    for (; j < jend; j += 2) {
        int e = j + half;
        bool ok = e < jend;
        int r = eidx[ok ? e : (jend - 1)];
        float m = ok ? 1.f : 0.f;
        uint4 v = xb[(size_t)((unsigned)r * 32u + fl)];
        a0 = fmaf(m, blo(v.x), a0);
        a1 = fmaf(m, bhi(v.x), a1);
        a2 = fmaf(m, blo(v.y), a2);
        a3 = fmaf(m, bhi(v.y), a3);
        a4 = fmaf(m, blo(v.z), a4);
        a5 = fmaf(m, bhi(v.z), a5);
        a6 = fmaf(m, blo(v.w), a6);
        a7 = fmaf(m, bhi(v.w), a7);
    }

    a0 += __shfl_xor(a0, 32);
    a1 += __shfl_xor(a1, 32);
    a2 += __shfl_xor(a2, 32);
    a3 += __shfl_xor(a3, 32);
    a4 += __shfl_xor(a4, 32);
    a5 += __shfl_xor(a5, 32);
    a6 += __shfl_xor(a6, 32);
    a7 += __shfl_xor(a7, 32);

    a0 += blo(sv.x); a1 += bhi(sv.x);
    a2 += blo(sv.y); a3 += bhi(sv.y);
    a4 += blo(sv.z); a5 += bhi(sv.z);
    a6 += blo(sv.w); a7 += bhi(sv.w);

    float d = dinv[c];
    float4 bb0 = ((const float4*)b1)[fl * 2];
    float4 bb1 = ((const float4*)b1)[fl * 2 + 1];
    float f0 = fmaxf(a0 * d + bb0.x, 0.f);
    float f1 = fmaxf(a1 * d + bb0.y, 0.f);
    float f2 = fmaxf(a2 * d + bb0.z, 0.f);
    float f3 = fmaxf(a3 * d + bb0.w, 0.f);
    float f4 = fmaxf(a4 * d + bb1.x, 0.f);
    float f5 = fmaxf(a5 * d + bb1.y, 0.f);
    float f6 = fmaxf(a6 * d + bb1.z, 0.f);
    float f7 = fmaxf(a7 * d + bb1.w, 0.f);
    u32x4 p;
    p.x = (unsigned int)f2bf(f0) | ((unsigned int)f2bf(f1) << 16);
    p.y = (unsigned int)f2bf(f2) | ((unsigned int)f2bf(f3) << 16);
    p.z = (unsigned int)f2bf(f4) | ((unsigned int)f2bf(f5) << 16);
    p.w = (unsigned int)f2bf(f6) | ((unsigned int)f2bf(f7) << 16);
    if (lane < 32)
        __builtin_nontemporal_store(p, (u32x4*)(h + (size_t)c * 256 + fl * 8));
}

// ---------------- layer 2 GEMM: t2p = bf16((h @ W2) * dinv), row stride 40 ----
// Only 3 j-frags (cols 0..47; 40 real). h loads non-temporal (read-once stream)
// so L2 keeps t2p (8MB) resident for spmm2's gather.

__global__ __launch_bounds__(256) void gemm2_kernel(const unsigned short* __restrict__ h,
                                                    const unsigned short* __restrict__ w2t,
                                                    const float* __restrict__ dinv,
                                                    unsigned short* __restrict__ t2p, int M) {
    __shared__ unsigned short As[64 * 264];
    __shared__ unsigned short Bs[64 * 264];
    int t = threadIdx.x;
    int m0 = blockIdx.x * 64;
    int lane = t & 63, wv = t >> 6;
    int lm = lane & 15, q = lane >> 4;

    #pragma unroll
    for (int i = 0; i < 8; i++) {
        int c = t + i * 256;
        int row = c >> 5, col = (c & 31) * 8;
        int m = m0 + row; if (m >= M) m = M - 1;
        u32x4 av = __builtin_nontemporal_load((const u32x4*)(h + (size_t)m * 256 + col));
        *(u32x4*)&As[row * 264 + col] = av;
        u32x4 bv = *(const u32x4*)(w2t + (size_t)row * 256 + col);
        *(u32x4*)&Bs[row * 264 + col] = bv;
    }
    __syncthreads();

    f32x4 acc[3];
    f32x4 z = {0.f, 0.f, 0.f, 0.f};
    #pragma unroll
    for (int j = 0; j < 3; j++) acc[j] = z;

    #pragma unroll
    for (int k0 = 0; k0 < 256; k0 += 32) {
        short8 af = *(const short8*)&As[(wv * 16 + lm) * 264 + k0 + q * 8];
        #pragma unroll
        for (int j = 0; j < 3; j++) {
            short8 bf = *(const short8*)&Bs[(j * 16 + lm) * 264 + k0 + q * 8];
            acc[j] = __builtin_amdgcn_mfma_f32_16x16x32_bf16(af, bf, acc[j], 0, 0, 0);
        }
    }

    #pragma unroll
    for (int r = 0; r < 4; r++) {
        int m = m0 + wv * 16 + q * 4 + r;
        if (m < M) {
            float d = dinv[m];
            #pragma unroll
            for (int j = 0; j < 3; j++) {
                int n = j * 16 + lm;
                if (n < 40)
                    t2p[(size_t)m * 40 + n] = f2bf(acc[j][r] * d);
            }
        }
    }
}

// ---------------- layer 2 aggregate + bias + log_softmax ----------------
// t2p rows are 80B (40 bf16). Lane l: edge slot g=l>>4, feature block fl=l&15
// (fl>=10 clamped, redundant). One dwordx2 instr = 4 edge rows.

__global__ __launch_bounds__(256) void spmm2_kernel(const unsigned short* __restrict__ t2p,
                                                    const int* __restrict__ colptr,
                                                    const int* __restrict__ eidx,
                                                    const float* __restrict__ dinv,
                                                    const float* __restrict__ b2,
                                                    float* __restrict__ out, int Nn) {
    int wid = threadIdx.x >> 6, lane = threadIdx.x & 63;
    int c = blockIdx.x * 4 + wid;
    if (c >= Nn) return;
    int g = lane >> 4;
    int fl = lane & 15;
    int flc = (fl < 10) ? fl : 9;
    const uint2* tb = (const uint2*)t2p;   // row stride = 10 uint2 (80B)

    uint2 sv = tb[(size_t)((unsigned)c * 10u + flc)];

    float a0 = 0.f, a1 = 0.f, a2 = 0.f, a3 = 0.f;
    int j = colptr[c], jend = colptr[c + 1];

    for (; j + 8 <= jend; j += 8) {
        int r0 = eidx[j     + g];
        int r1 = eidx[j + 4 + g];
        uint2 v0 = tb[(size_t)((unsigned)r0 * 10u + flc)];
        uint2 v1 = tb[(size_t)((unsigned)r1 * 10u + flc)];
        a0 += blo(v0.x) + blo(v1.x);
        a1 += bhi(v0.x) + bhi(v1.x);
        a2 += blo(v0.y) + blo(v1.y);
        a3 += bhi(v0.y) + bhi(v1.y);
    }
    for (; j < jend; j += 4) {
        int e = j + g;
        bool ok = e < jend;
        int r = eidx[ok ? e : (jend - 1)];
        float m = ok ? 1.f : 0.f;
        uint2 v = tb[(size_t)((unsigned)r * 10u + flc)];
        a0 = fmaf(m, blo(v.x), a0);
        a1 = fmaf(m, bhi(v.x), a1);
        a2 = fmaf(m, blo(v.y), a2);
        a3 = fmaf(m, bhi(v.y), a3);
    }

    a0 += __shfl_xor(a0, 16); a0 += __shfl_xor(a0, 32);
    a1 += __shfl_xor(a1, 16); a1 += __shfl_xor(a1, 32);
    a2 += __shfl_xor(a2, 16); a2 += __shfl_xor(a2, 32);
    a3 += __shfl_xor(a3, 16); a3 += __shfl_xor(a3, 32);

    a0 += blo(sv.x); a1 += bhi(sv.x);
    a2 += blo(sv.y); a3 += bhi(sv.y);

    float d = dinv[c];
    bool valid = fl < 10;
    float4 bb = {0.f, 0.f, 0.f, 0.f};
    if (valid) bb = ((const float4*)b2)[fl];
    float v0 = valid ? (a0 * d + bb.x) : -INFINITY;
    float v1 = valid ? (a1 * d + bb.y) : -INFINITY;
    float v2 = valid ? (a2 * d + bb.z) : -INFINITY;
    float v3 = valid ? (a3 * d + bb.w) : -INFINITY;

    float mx = fmaxf(fmaxf(v0, v1), fmaxf(v2, v3));
    #pragma unroll
    for (int o = 8; o > 0; o >>= 1) { float z = __shfl_xor(mx, o); mx = fmaxf(mx, z); }
    float ex = valid ? (expf(v0 - mx) + expf(v1 - mx) + expf(v2 - mx) + expf(v3 - mx)) : 0.f;
    #pragma unroll
    for (int o = 8; o > 0; o >>= 1) ex += __shfl_xor(ex, o);
    float ls = logf(ex);

    if (lane < 10) {
        float4 o4;
        o4.x = v0 - mx - ls;
        o4.y = v1 - mx - ls;
        o4.z = v2 - mx - ls;
        o4.w = v3 - mx - ls;
        *(float4*)(out + (size_t)c * 40 + fl * 4) = o4;
    }
}

// ---------------- launcher ----------------

extern "C" void kernel_launch(void* const* d_in, const int* in_sizes, int n_in,
                              void* d_out, int out_size, void* d_ws, size_t ws_size,
                              hipStream_t stream) {
    const float* x  = (const float*)d_in[0];
    const int*   ei = (const int*)d_in[1];
    const float* W1 = (const float*)d_in[2];
    const float* b1 = (const float*)d_in[3];
    const float* W2 = (const float*)d_in[4];
    const float* b2 = (const float*)d_in[5];
    float* out = (float*)d_out;

    int N = in_sizes[0] / 512;   // 100000
    int E = in_sizes[1] / 2;     // 3200000

    char* p = (char*)d_ws;
    auto carve = [&](size_t bytes) -> char* {
        char* q = p;
        p += (bytes + 1023) & ~(size_t)1023;
        return q;
    };
    float* dinv   = (float*)carve((size_t)N * 4);
    int*   cnt    = (int*)carve((size_t)N * 4);
    int*   colptr = (int*)carve(((size_t)N + 1) * 4);
    int*   fillc  = (int*)carve((size_t)N * 4);
    int*   bsum   = (int*)carve(1024 * 4);
    int*   eidx   = (int*)carve((size_t)E * 4);
    unsigned short* w1t = (unsigned short*)carve((size_t)256 * 512 * 2);
    unsigned short* w2t = (unsigned short*)carve((size_t)64 * 256 * 2);
    unsigned short* xs  = (unsigned short*)carve((size_t)N * 256 * 2);
    unsigned short* h   = (unsigned short*)carve((size_t)N * 256 * 2);
    unsigned short* t2p = (unsigned short*)carve((size_t)N * 40 * 2);

    hipMemsetAsync(cnt,   0, (size_t)N * 4, stream);
    hipMemsetAsync(fillc, 0, (size_t)N * 4, stream);

    int eb = (E + 255) / 256;
    int nb = (N + 511) / 512;

    count_kernel<<<eb, 256, 0, stream>>>(ei, cnt, E);
    scanA_kernel<<<nb, 256, 0, stream>>>(cnt, dinv, colptr, bsum, N);
    scanB_kernel<<<1, 256, 0, stream>>>(bsum, nb);
    scanC_kernel<<<nb, 256, 0, stream>>>(colptr, bsum, N, E);
    fill_kernel<<<eb, 256, 0, stream>>>(ei, colptr, fillc, eidx, E);
    prep_w_kernel<<<576, 256, 0, stream>>>(W1, W2, w1t, w2t);

    int mb = (N + 63) / 64;
    gemm1_kernel<<<mb, 256, 0, stream>>>(x, w1t, dinv, xs, N);
    spmm1_kernel<<<(N + 3) / 4, 256, 0, stream>>>(xs, colptr, eidx, dinv, b1, h, N);
    gemm2_kernel<<<mb, 256, 0, stream>>>(h, w2t, dinv, t2p, N);
    spmm2_kernel<<<(N + 3) / 4, 256, 0, stream>>>(t2p, colptr, eidx, dinv, b2, out, N);
}

// Round 5
// 934.728 us; speedup vs baseline: 1.0217x; 1.0217x over previous
//
#include <hip/hip_runtime.h>
#include <math.h>

typedef __attribute__((ext_vector_type(8))) short short8;
typedef __attribute__((ext_vector_type(4))) float f32x4;
typedef __attribute__((ext_vector_type(4))) unsigned int u32x4;

static __device__ __forceinline__ unsigned short f2bf(float f) {
    unsigned int u = __float_as_uint(f);
    unsigned int r = (u + 0x7FFFu + ((u >> 16) & 1u)) >> 16;
    return (unsigned short)r;
}
static __device__ __forceinline__ float blo(unsigned int u) { return __uint_as_float(u << 16); }
static __device__ __forceinline__ float bhi(unsigned int u) { return __uint_as_float(u & 0xFFFF0000u); }

// ---------------- graph build ----------------

__global__ void count_kernel(const int* __restrict__ ei, int* __restrict__ cnt, int E) {
    int e = blockIdx.x * 256 + threadIdx.x;
    if (e < E) atomicAdd(&cnt[ei[E + e]], 1);
}

__global__ void scanA_kernel(const int* __restrict__ cnt, float* __restrict__ dinv,
                             int* __restrict__ colptr, int* __restrict__ bsum, int n) {
    __shared__ int s[256];
    int b = blockIdx.x, t = threadIdx.x;
    int i = b * 512 + 2 * t;
    int c0 = (i     < n) ? cnt[i]     : 0;
    int c1 = (i + 1 < n) ? cnt[i + 1] : 0;
    if (i     < n) dinv[i]     = rsqrtf((float)(c0 + 1));
    if (i + 1 < n) dinv[i + 1] = rsqrtf((float)(c1 + 1));
    int v = c0 + c1;
    s[t] = v;
    __syncthreads();
    #pragma unroll
    for (int o = 1; o < 256; o <<= 1) {
        int x = (t >= o) ? s[t - o] : 0;
        __syncthreads();
        s[t] += x;
        __syncthreads();
    }
    int excl = s[t] - v;
    if (i     < n) colptr[i]     = excl;
    if (i + 1 < n) colptr[i + 1] = excl + c0;
    if (t == 255) bsum[b] = s[t];
}

__global__ void scanB_kernel(int* bsum, int nb) {
    __shared__ int s[256];
    int t = threadIdx.x;
    int v = (t < nb) ? bsum[t] : 0;
    s[t] = v;
    __syncthreads();
    #pragma unroll
    for (int o = 1; o < 256; o <<= 1) {
        int x = (t >= o) ? s[t - o] : 0;
        __syncthreads();
        s[t] += x;
        __syncthreads();
    }
    if (t < nb) bsum[t] = s[t] - v;
}

__global__ void scanC_kernel(int* __restrict__ colptr, const int* __restrict__ bsum,
                             int n, int E) {
    int b = blockIdx.x, t = threadIdx.x;
    int off = bsum[b];
    int i = b * 512 + 2 * t;
    if (i     < n) colptr[i]     += off;
    if (i + 1 < n) colptr[i + 1] += off;
    if (b == 0 && t == 0) colptr[n] = E;
}

__global__ void fill_kernel(const int* __restrict__ ei, const int* __restrict__ colptr,
                            int* __restrict__ fillc, int* __restrict__ eidx, int E) {
    int e = blockIdx.x * 256 + threadIdx.x;
    if (e < E) {
        int r = ei[e];
        int c = ei[E + e];
        int pos = colptr[c] + atomicAdd(&fillc[c], 1);
        eidx[pos] = r;
    }
}

// W1 [512][256] -> w1t [256][512] bf16 ; W2 [256][40] -> w2t [64][256] bf16 (pad 0)
__global__ void prep_w_kernel(const float* __restrict__ W1, const float* __restrict__ W2,
                              unsigned short* __restrict__ w1t, unsigned short* __restrict__ w2t) {
    int id = blockIdx.x * 256 + threadIdx.x;
    if (id < 512 * 256) {
        int k = id >> 8, n = id & 255;
        w1t[(size_t)n * 512 + k] = f2bf(W1[id]);
    } else {
        int id2 = id - 512 * 256;
        if (id2 < 64 * 256) {
            int n = id2 >> 8, k = id2 & 255;
            w2t[id2] = (n < 40) ? f2bf(W2[k * 40 + n]) : (unsigned short)0;
        }
    }
}

// ---------------- layer 1 GEMM ----------------
// xs = bf16((x @ W1) * dinv[row]). Tile 64(m) x 256(n), BK=32.
// A (x, fp32->bf16) staged in LDS (shared by all 4 waves, converted once).
// B (w1t) rows are wave-exclusive -> loaded DIRECTLY global->reg (L2-hot, 256KB),
// double-buffered in registers. No B LDS.

__global__ __launch_bounds__(256) void gemm1_kernel(const float* __restrict__ x,
                                                    const unsigned short* __restrict__ w1t,
                                                    const float* __restrict__ dinv,
                                                    unsigned short* __restrict__ xs, int M) {
    __shared__ unsigned short As[2][64 * 40];
    int t = threadIdx.x;
    int m0 = blockIdx.x * 64;
    int lane = t & 63, wv = t >> 6;
    int wn = wv * 64;
    int lm = lane & 15, q = lane >> 4;

    int ra = t >> 2, kc = (t & 3) * 8;
    int am = m0 + ra; if (am >= M) am = M - 1;
    const float* Ap = x + (size_t)am * 512 + kc;
    const unsigned short* Bq = w1t + (size_t)(wn + lm) * 512 + q * 8;

    f32x4 acc[4][4];
    f32x4 z = {0.f, 0.f, 0.f, 0.f};
    #pragma unroll
    for (int i = 0; i < 4; i++)
        #pragma unroll
        for (int j = 0; j < 4; j++) acc[i][j] = z;

    // prologue: stage A k=0 chunk; load B k=0 frags
    f32x4 a0 = *(const f32x4*)(Ap + 0);
    f32x4 a1 = *(const f32x4*)(Ap + 4);
    u32x4 bcur[4];
    #pragma unroll
    for (int j = 0; j < 4; j++) bcur[j] = *(const u32x4*)(Bq + j * 16 * 512);
    {
        u32x4 ap;
        ap.x = (unsigned int)f2bf(a0.x) | ((unsigned int)f2bf(a0.y) << 16);
        ap.y = (unsigned int)f2bf(a0.z) | ((unsigned int)f2bf(a0.w) << 16);
        ap.z = (unsigned int)f2bf(a1.x) | ((unsigned int)f2bf(a1.y) << 16);
        ap.w = (unsigned int)f2bf(a1.z) | ((unsigned int)f2bf(a1.w) << 16);
        *(u32x4*)&As[0][ra * 40 + kc] = ap;
    }
    __syncthreads();

    int buf = 0;
    for (int k0 = 0; k0 < 512; k0 += 32) {
        bool more = (k0 + 32) < 512;
        f32x4 na0, na1;
        u32x4 bnext[4];
        if (more) {
            na0 = *(const f32x4*)(Ap + k0 + 32);
            na1 = *(const f32x4*)(Ap + k0 + 36);
            #pragma unroll
            for (int j = 0; j < 4; j++)
                bnext[j] = *(const u32x4*)(Bq + j * 16 * 512 + k0 + 32);
        }
        short8 af[4];
        #pragma unroll
        for (int i = 0; i < 4; i++)
            af[i] = *(const short8*)&As[buf][(i * 16 + lm) * 40 + q * 8];
        #pragma unroll
        for (int i = 0; i < 4; i++)
            #pragma unroll
            for (int j = 0; j < 4; j++)
                acc[i][j] = __builtin_amdgcn_mfma_f32_16x16x32_bf16(af[i], *(const short8*)&bcur[j], acc[i][j], 0, 0, 0);
        if (more) {
            u32x4 ap;
            ap.x = (unsigned int)f2bf(na0.x) | ((unsigned int)f2bf(na0.y) << 16);
            ap.y = (unsigned int)f2bf(na0.z) | ((unsigned int)f2bf(na0.w) << 16);
            ap.z = (unsigned int)f2bf(na1.x) | ((unsigned int)f2bf(na1.y) << 16);
            ap.w = (unsigned int)f2bf(na1.z) | ((unsigned int)f2bf(na1.w) << 16);
            *(u32x4*)&As[buf ^ 1][ra * 40 + kc] = ap;
            __syncthreads();
            #pragma unroll
            for (int j = 0; j < 4; j++) bcur[j] = bnext[j];
        }
        buf ^= 1;
    }

    #pragma unroll
    for (int i = 0; i < 4; i++) {
        #pragma unroll
        for (int r = 0; r < 4; r++) {
            int m = m0 + i * 16 + q * 4 + r;
            if (m < M) {
                float d = dinv[m];
                #pragma unroll
                for (int j = 0; j < 4; j++) {
                    int n = wn + j * 16 + lm;
                    xs[(size_t)m * 256 + n] = f2bf(acc[i][j][r] * d);
                }
            }
        }
    }
}

// ---------------- layer 1 aggregate ----------------
// One wave per column. Lane l covers features (l&31)*8..+7 via uint4 (16B);
// lanes 0-31 even edges, 32-63 odd edges. 8 edges/iter in flight.

__global__ __launch_bounds__(256) void spmm1_kernel(const unsigned short* __restrict__ xs,
                                                    const int* __restrict__ colptr,
                                                    const int* __restrict__ eidx,
                                                    const float* __restrict__ dinv,
                                                    const float* __restrict__ b1,
                                                    unsigned short* __restrict__ h, int Nn) {
    int wid = threadIdx.x >> 6, lane = threadIdx.x & 63;
    int c = blockIdx.x * 4 + wid;
    if (c >= Nn) return;
    int half = lane >> 5;
    int fl = lane & 31;
    const uint4* xb = (const uint4*)xs;

    uint4 sv = xb[(size_t)((unsigned)c * 32u + fl)];

    float a0 = 0.f, a1 = 0.f, a2 = 0.f, a3 = 0.f;
    float a4 = 0.f, a5 = 0.f, a6 = 0.f, a7 = 0.f;

    int j = colptr[c], jend = colptr[c + 1];

    for (; j + 8 <= jend; j += 8) {
        int r0 = eidx[j     + half];
        int r1 = eidx[j + 2 + half];
        int r2 = eidx[j + 4 + half];
        int r3 = eidx[j + 6 + half];
        uint4 v0 = xb[(size_t)((unsigned)r0 * 32u + fl)];
        uint4 v1 = xb[(size_t)((unsigned)r1 * 32u + fl)];
        uint4 v2 = xb[(size_t)((unsigned)r2 * 32u + fl)];
        uint4 v3 = xb[(size_t)((unsigned)r3 * 32u + fl)];
        a0 += (blo(v0.x) + blo(v1.x)) + (blo(v2.x) + blo(v3.x));
        a1 += (bhi(v0.x) + bhi(v1.x)) + (bhi(v2.x) + bhi(v3.x));
        a2 += (blo(v0.y) + blo(v1.y)) + (blo(v2.y) + blo(v3.y));
        a3 += (bhi(v0.y) + bhi(v1.y)) + (bhi(v2.y) + bhi(v3.y));
        a4 += (blo(v0.z) + blo(v1.z)) + (blo(v2.z) + blo(v3.z));
        a5 += (bhi(v0.z) + bhi(v1.z)) + (bhi(v2.z) + bhi(v3.z));
        a6 += (blo(v0.w) + blo(v1.w)) + (blo(v2.w) + blo(v3.w));
        a7 += (bhi(v0.w) + bhi(v1.w)) + (bhi(v2.w) + bhi(v3.w));
    }
    for (; j < jend; j += 2) {
        int e = j + half;
        bool ok = e < jend;
        int r = eidx[ok ? e : (jend - 1)];
        float m = ok ? 1.f : 0.f;
        uint4 v = xb[(size_t)((unsigned)r * 32u + fl)];
        a0 = fmaf(m, blo(v.x), a0);
        a1 = fmaf(m, bhi(v.x), a1);
        a2 = fmaf(m, blo(v.y), a2);
        a3 = fmaf(m, bhi(v.y), a3);
        a4 = fmaf(m, blo(v.z), a4);
        a5 = fmaf(m, bhi(v.z), a5);
        a6 = fmaf(m, blo(v.w), a6);
        a7 = fmaf(m, bhi(v.w), a7);
    }

    a0 += __shfl_xor(a0, 32);
    a1 += __shfl_xor(a1, 32);
    a2 += __shfl_xor(a2, 32);
    a3 += __shfl_xor(a3, 32);
    a4 += __shfl_xor(a4, 32);
    a5 += __shfl_xor(a5, 32);
    a6 += __shfl_xor(a6, 32);
    a7 += __shfl_xor(a7, 32);

    a0 += blo(sv.x); a1 += bhi(sv.x);
    a2 += blo(sv.y); a3 += bhi(sv.y);
    a4 += blo(sv.z); a5 += bhi(sv.z);
    a6 += blo(sv.w); a7 += bhi(sv.w);

    float d = dinv[c];
    float4 bb0 = ((const float4*)b1)[fl * 2];
    float4 bb1 = ((const float4*)b1)[fl * 2 + 1];
    float f0 = fmaxf(a0 * d + bb0.x, 0.f);
    float f1 = fmaxf(a1 * d + bb0.y, 0.f);
    float f2 = fmaxf(a2 * d + bb0.z, 0.f);
    float f3 = fmaxf(a3 * d + bb0.w, 0.f);
    float f4 = fmaxf(a4 * d + bb1.x, 0.f);
    float f5 = fmaxf(a5 * d + bb1.y, 0.f);
    float f6 = fmaxf(a6 * d + bb1.z, 0.f);
    float f7 = fmaxf(a7 * d + bb1.w, 0.f);
    uint4 p;
    p.x = (unsigned int)f2bf(f0) | ((unsigned int)f2bf(f1) << 16);
    p.y = (unsigned int)f2bf(f2) | ((unsigned int)f2bf(f3) << 16);
    p.z = (unsigned int)f2bf(f4) | ((unsigned int)f2bf(f5) << 16);
    p.w = (unsigned int)f2bf(f6) | ((unsigned int)f2bf(f7) << 16);
    if (lane < 32)
        *(uint4*)(h + (size_t)c * 256 + fl * 8) = p;
}

// ---------------- layer 2 GEMM: t2p = bf16((h @ W2) * dinv) ----
// t2p rows padded to 64 shorts (128B, line-aligned). Only 3 j-frags (cols 0..47).

__global__ __launch_bounds__(256) void gemm2_kernel(const unsigned short* __restrict__ h,
                                                    const unsigned short* __restrict__ w2t,
                                                    const float* __restrict__ dinv,
                                                    unsigned short* __restrict__ t2p, int M) {
    __shared__ unsigned short As[64 * 264];
    __shared__ unsigned short Bs[64 * 264];
    int t = threadIdx.x;
    int m0 = blockIdx.x * 64;
    int lane = t & 63, wv = t >> 6;
    int lm = lane & 15, q = lane >> 4;

    #pragma unroll
    for (int i = 0; i < 8; i++) {
        int c = t + i * 256;
        int row = c >> 5, col = (c & 31) * 8;
        int m = m0 + row; if (m >= M) m = M - 1;
        uint4 av = *(const uint4*)(h + (size_t)m * 256 + col);
        *(uint4*)&As[row * 264 + col] = av;
        uint4 bv = *(const uint4*)(w2t + (size_t)row * 256 + col);
        *(uint4*)&Bs[row * 264 + col] = bv;
    }
    __syncthreads();

    f32x4 acc[3];
    f32x4 z = {0.f, 0.f, 0.f, 0.f};
    #pragma unroll
    for (int j = 0; j < 3; j++) acc[j] = z;

    #pragma unroll
    for (int k0 = 0; k0 < 256; k0 += 32) {
        short8 af = *(const short8*)&As[(wv * 16 + lm) * 264 + k0 + q * 8];
        #pragma unroll
        for (int j = 0; j < 3; j++) {
            short8 bf = *(const short8*)&Bs[(j * 16 + lm) * 264 + k0 + q * 8];
            acc[j] = __builtin_amdgcn_mfma_f32_16x16x32_bf16(af, bf, acc[j], 0, 0, 0);
        }
    }

    #pragma unroll
    for (int r = 0; r < 4; r++) {
        int m = m0 + wv * 16 + q * 4 + r;
        if (m < M) {
            float d = dinv[m];
            #pragma unroll
            for (int j = 0; j < 3; j++) {
                int n = j * 16 + lm;
                t2p[(size_t)m * 64 + n] = f2bf(acc[j][r] * d);
            }
        }
    }
}

// ---------------- layer 2 aggregate + bias + log_softmax ----------------
// t2p rows 128B aligned. Lane l: edge slot g=l>>3 (8 slots), feature block fl=l&7
// covering features fl*8..+7 via u32x4 (fl<5 valid; 5-7 clamp-read same line).
// One dwordx4 instr = 8 edge rows; 16 edges in flight with 2 loads/iter.

__global__ __launch_bounds__(256) void spmm2_kernel(const unsigned short* __restrict__ t2p,
                                                    const int* __restrict__ colptr,
                                                    const int* __restrict__ eidx,
                                                    const float* __restrict__ dinv,
                                                    const float* __restrict__ b2,
                                                    float* __restrict__ out, int Nn) {
    int wid = threadIdx.x >> 6, lane = threadIdx.x & 63;
    int c = blockIdx.x * 4 + wid;
    if (c >= Nn) return;
    int g = lane >> 3;           // edge slot 0..7
    int fl = lane & 7;           // feature block: features fl*8..+7
    int flc = (fl < 5) ? fl : 4;
    const u32x4* tb = (const u32x4*)t2p;   // row stride = 8 u32x4 (128B)

    u32x4 sv = tb[(size_t)((unsigned)c * 8u + flc)];

    float a0 = 0.f, a1 = 0.f, a2 = 0.f, a3 = 0.f;
    float a4 = 0.f, a5 = 0.f, a6 = 0.f, a7 = 0.f;
    int j = colptr[c], jend = colptr[c + 1];

    for (; j + 16 <= jend; j += 16) {
        int r0 = eidx[j     + g];
        int r1 = eidx[j + 8 + g];
        u32x4 v0 = tb[(size_t)((unsigned)r0 * 8u + flc)];
        u32x4 v1 = tb[(size_t)((unsigned)r1 * 8u + flc)];
        a0 += blo(v0.x) + blo(v1.x);
        a1 += bhi(v0.x) + bhi(v1.x);
        a2 += blo(v0.y) + blo(v1.y);
        a3 += bhi(v0.y) + bhi(v1.y);
        a4 += blo(v0.z) + blo(v1.z);
        a5 += bhi(v0.z) + bhi(v1.z);
        a6 += blo(v0.w) + blo(v1.w);
        a7 += bhi(v0.w) + bhi(v1.w);
    }
    for (; j < jend; j += 8) {
        int e = j + g;
        bool ok = e < jend;
        int r = eidx[ok ? e : (jend - 1)];
        float m = ok ? 1.f : 0.f;
        u32x4 v = tb[(size_t)((unsigned)r * 8u + flc)];
        a0 = fmaf(m, blo(v.x), a0);
        a1 = fmaf(m, bhi(v.x), a1);
        a2 = fmaf(m, blo(v.y), a2);
        a3 = fmaf(m, bhi(v.y), a3);
        a4 = fmaf(m, blo(v.z), a4);
        a5 = fmaf(m, bhi(v.z), a5);
        a6 = fmaf(m, blo(v.w), a6);
        a7 = fmaf(m, bhi(v.w), a7);
    }

    // fold 8 edge groups (lane bits 3,4,5)
    #pragma unroll
    for (int o = 8; o <= 32; o <<= 1) {
        a0 += __shfl_xor(a0, o);
        a1 += __shfl_xor(a1, o);
        a2 += __shfl_xor(a2, o);
        a3 += __shfl_xor(a3, o);
        a4 += __shfl_xor(a4, o);
        a5 += __shfl_xor(a5, o);
        a6 += __shfl_xor(a6, o);
        a7 += __shfl_xor(a7, o);
    }

    // self contribution (same in all groups)
    a0 += blo(sv.x); a1 += bhi(sv.x);
    a2 += blo(sv.y); a3 += bhi(sv.y);
    a4 += blo(sv.z); a5 += bhi(sv.z);
    a6 += blo(sv.w); a7 += bhi(sv.w);

    float d = dinv[c];
    bool valid = fl < 5;                  // features fl*8..+7 < 40
    float4 bb0 = {0.f, 0.f, 0.f, 0.f}, bb1 = {0.f, 0.f, 0.f, 0.f};
    if (valid) {
        bb0 = ((const float4*)b2)[fl * 2];
        bb1 = ((const float4*)b2)[fl * 2 + 1];
    }
    float v0 = valid ? (a0 * d + bb0.x) : -INFINITY;
    float v1 = valid ? (a1 * d + bb0.y) : -INFINITY;
    float v2 = valid ? (a2 * d + bb0.z) : -INFINITY;
    float v3 = valid ? (a3 * d + bb0.w) : -INFINITY;
    float v4 = valid ? (a4 * d + bb1.x) : -INFINITY;
    float v5 = valid ? (a5 * d + bb1.y) : -INFINITY;
    float v6 = valid ? (a6 * d + bb1.z) : -INFINITY;
    float v7 = valid ? (a7 * d + bb1.w) : -INFINITY;

    float mx = fmaxf(fmaxf(fmaxf(v0, v1), fmaxf(v2, v3)),
                     fmaxf(fmaxf(v4, v5), fmaxf(v6, v7)));
    #pragma unroll
    for (int o = 1; o <= 4; o <<= 1) { float zz = __shfl_xor(mx, o); mx = fmaxf(mx, zz); }
    float ex = valid ? (expf(v0 - mx) + expf(v1 - mx) + expf(v2 - mx) + expf(v3 - mx)
                      + expf(v4 - mx) + expf(v5 - mx) + expf(v6 - mx) + expf(v7 - mx)) : 0.f;
    #pragma unroll
    for (int o = 1; o <= 4; o <<= 1) ex += __shfl_xor(ex, o);
    float ls = logf(ex);

    if (lane < 5) {   // g==0, fl<5
        float4 oa, ob;
        oa.x = v0 - mx - ls; oa.y = v1 - mx - ls;
        oa.z = v2 - mx - ls; oa.w = v3 - mx - ls;
        ob.x = v4 - mx - ls; ob.y = v5 - mx - ls;
        ob.z = v6 - mx - ls; ob.w = v7 - mx - ls;
        *(float4*)(out + (size_t)c * 40 + fl * 8)     = oa;
        *(float4*)(out + (size_t)c * 40 + fl * 8 + 4) = ob;
    }
}

// ---------------- launcher ----------------

extern "C" void kernel_launch(void* const* d_in, const int* in_sizes, int n_in,
                              void* d_out, int out_size, void* d_ws, size_t ws_size,
                              hipStream_t stream) {
    const float* x  = (const float*)d_in[0];
    const int*   ei = (const int*)d_in[1];
    const float* W1 = (const float*)d_in[2];
    const float* b1 = (const float*)d_in[3];
    const float* W2 = (const float*)d_in[4];
    const float* b2 = (const float*)d_in[5];
    float* out = (float*)d_out;

    int N = in_sizes[0] / 512;   // 100000
    int E = in_sizes[1] / 2;     // 3200000

    char* p = (char*)d_ws;
    auto carve = [&](size_t bytes) -> char* {
        char* q = p;
        p += (bytes + 1023) & ~(size_t)1023;
        return q;
    };
    float* dinv   = (float*)carve((size_t)N * 4);
    int*   cnt    = (int*)carve((size_t)N * 4);
    int*   colptr = (int*)carve(((size_t)N + 1) * 4);
    int*   fillc  = (int*)carve((size_t)N * 4);
    int*   bsum   = (int*)carve(1024 * 4);
    int*   eidx   = (int*)carve((size_t)E * 4);
    unsigned short* w1t = (unsigned short*)carve((size_t)256 * 512 * 2);
    unsigned short* w2t = (unsigned short*)carve((size_t)64 * 256 * 2);
    unsigned short* xs  = (unsigned short*)carve((size_t)N * 256 * 2);
    unsigned short* h   = (unsigned short*)carve((size_t)N * 256 * 2);
    unsigned short* t2p = (unsigned short*)carve((size_t)N * 64 * 2);

    hipMemsetAsync(cnt,   0, (size_t)N * 4, stream);
    hipMemsetAsync(fillc, 0, (size_t)N * 4, stream);
    hipMemsetAsync(t2p,   0, (size_t)N * 64 * 2, stream);

    int eb = (E + 255) / 256;
    int nb = (N + 511) / 512;

    count_kernel<<<eb, 256, 0, stream>>>(ei, cnt, E);
    scanA_kernel<<<nb, 256, 0, stream>>>(cnt, dinv, colptr, bsum, N);
    scanB_kernel<<<1, 256, 0, stream>>>(bsum, nb);
    scanC_kernel<<<nb, 256, 0, stream>>>(colptr, bsum, N, E);
    fill_kernel<<<eb, 256, 0, stream>>>(ei, colptr, fillc, eidx, E);
    prep_w_kernel<<<576, 256, 0, stream>>>(W1, W2, w1t, w2t);

    int mb = (N + 63) / 64;
    gemm1_kernel<<<mb, 256, 0, stream>>>(x, w1t, dinv, xs, N);
    spmm1_kernel<<<(N + 3) / 4, 256, 0, stream>>>(xs, colptr, eidx, dinv, b1, h, N);
    gemm2_kernel<<<mb, 256, 0, stream>>>(h, w2t, dinv, t2p, N);
    spmm2_kernel<<<(N + 3) / 4, 256, 0, stream>>>(t2p, colptr, eidx, dinv, b2, out, N);
}

// Round 6
// 918.705 us; speedup vs baseline: 1.0396x; 1.0174x over previous
//
#include <hip/hip_runtime.h>
#include <math.h>

typedef __attribute__((ext_vector_type(8))) short short8;
typedef __attribute__((ext_vector_type(4))) float f32x4;
typedef __attribute__((ext_vector_type(4))) unsigned int u32x4;

static __device__ __forceinline__ unsigned short f2bf(float f) {
    unsigned int u = __float_as_uint(f);
    unsigned int r = (u + 0x7FFFu + ((u >> 16) & 1u)) >> 16;
    return (unsigned short)r;
}
static __device__ __forceinline__ float blo(unsigned int u) { return __uint_as_float(u << 16); }
static __device__ __forceinline__ float bhi(unsigned int u) { return __uint_as_float(u & 0xFFFF0000u); }

// ---------------- graph build ----------------

__global__ void count_kernel(const int* __restrict__ ei, int* __restrict__ cnt, int E) {
    int e = blockIdx.x * 256 + threadIdx.x;
    if (e < E) atomicAdd(&cnt[ei[E + e]], 1);
}

__global__ void scanA_kernel(const int* __restrict__ cnt, float* __restrict__ dinv,
                             int* __restrict__ colptr, int* __restrict__ bsum, int n) {
    __shared__ int s[256];
    int b = blockIdx.x, t = threadIdx.x;
    int i = b * 512 + 2 * t;
    int c0 = (i     < n) ? cnt[i]     : 0;
    int c1 = (i + 1 < n) ? cnt[i + 1] : 0;
    if (i     < n) dinv[i]     = rsqrtf((float)(c0 + 1));
    if (i + 1 < n) dinv[i + 1] = rsqrtf((float)(c1 + 1));
    int v = c0 + c1;
    s[t] = v;
    __syncthreads();
    #pragma unroll
    for (int o = 1; o < 256; o <<= 1) {
        int x = (t >= o) ? s[t - o] : 0;
        __syncthreads();
        s[t] += x;
        __syncthreads();
    }
    int excl = s[t] - v;
    if (i     < n) colptr[i]     = excl;
    if (i + 1 < n) colptr[i + 1] = excl + c0;
    if (t == 255) bsum[b] = s[t];
}

__global__ void scanB_kernel(int* bsum, int nb) {
    __shared__ int s[256];
    int t = threadIdx.x;
    int v = (t < nb) ? bsum[t] : 0;
    s[t] = v;
    __syncthreads();
    #pragma unroll
    for (int o = 1; o < 256; o <<= 1) {
        int x = (t >= o) ? s[t - o] : 0;
        __syncthreads();
        s[t] += x;
        __syncthreads();
    }
    if (t < nb) bsum[t] = s[t] - v;
}

__global__ void scanC_kernel(int* __restrict__ colptr, const int* __restrict__ bsum,
                             int n, int E) {
    int b = blockIdx.x, t = threadIdx.x;
    int off = bsum[b];
    int i = b * 512 + 2 * t;
    if (i     < n) colptr[i]     += off;
    if (i + 1 < n) colptr[i + 1] += off;
    if (b == 0 && t == 0) colptr[n] = E;
}

__global__ void fill_kernel(const int* __restrict__ ei, const int* __restrict__ colptr,
                            int* __restrict__ fillc, int* __restrict__ eidx, int E) {
    int e = blockIdx.x * 256 + threadIdx.x;
    if (e < E) {
        int r = ei[e];
        int c = ei[E + e];
        int pos = colptr[c] + atomicAdd(&fillc[c], 1);
        eidx[pos] = r;
    }
}

// W1 [512][256] -> w1t [256][512] bf16 ; W2 [256][40] -> w2t [64][256] bf16 (pad 0)
__global__ void prep_w_kernel(const float* __restrict__ W1, const float* __restrict__ W2,
                              unsigned short* __restrict__ w1t, unsigned short* __restrict__ w2t) {
    int id = blockIdx.x * 256 + threadIdx.x;
    if (id < 512 * 256) {
        int k = id >> 8, n = id & 255;
        w1t[(size_t)n * 512 + k] = f2bf(W1[id]);
    } else {
        int id2 = id - 512 * 256;
        if (id2 < 64 * 256) {
            int n = id2 >> 8, k = id2 & 255;
            w2t[id2] = (n < 40) ? f2bf(W2[k * 40 + n]) : (unsigned short)0;
        }
    }
}

// ---------------- layer 1 GEMM ----------------
// xs = bf16((x @ W1) * dinv[row]). Tile 64(m) x 256(n), BK=32.
// A (x, fp32->bf16) staged in LDS; B (w1t) direct global->reg double-buffered.

__global__ __launch_bounds__(256) void gemm1_kernel(const float* __restrict__ x,
                                                    const unsigned short* __restrict__ w1t,
                                                    const float* __restrict__ dinv,
                                                    unsigned short* __restrict__ xs, int M) {
    __shared__ unsigned short As[2][64 * 40];
    int t = threadIdx.x;
    int m0 = blockIdx.x * 64;
    int lane = t & 63, wv = t >> 6;
    int wn = wv * 64;
    int lm = lane & 15, q = lane >> 4;

    int ra = t >> 2, kc = (t & 3) * 8;
    int am = m0 + ra; if (am >= M) am = M - 1;
    const float* Ap = x + (size_t)am * 512 + kc;
    const unsigned short* Bq = w1t + (size_t)(wn + lm) * 512 + q * 8;

    f32x4 acc[4][4];
    f32x4 z = {0.f, 0.f, 0.f, 0.f};
    #pragma unroll
    for (int i = 0; i < 4; i++)
        #pragma unroll
        for (int j = 0; j < 4; j++) acc[i][j] = z;

    f32x4 a0 = *(const f32x4*)(Ap + 0);
    f32x4 a1 = *(const f32x4*)(Ap + 4);
    u32x4 bcur[4];
    #pragma unroll
    for (int j = 0; j < 4; j++) bcur[j] = *(const u32x4*)(Bq + j * 16 * 512);
    {
        u32x4 ap;
        ap.x = (unsigned int)f2bf(a0.x) | ((unsigned int)f2bf(a0.y) << 16);
        ap.y = (unsigned int)f2bf(a0.z) | ((unsigned int)f2bf(a0.w) << 16);
        ap.z = (unsigned int)f2bf(a1.x) | ((unsigned int)f2bf(a1.y) << 16);
        ap.w = (unsigned int)f2bf(a1.z) | ((unsigned int)f2bf(a1.w) << 16);
        *(u32x4*)&As[0][ra * 40 + kc] = ap;
    }
    __syncthreads();

    int buf = 0;
    for (int k0 = 0; k0 < 512; k0 += 32) {
        bool more = (k0 + 32) < 512;
        f32x4 na0, na1;
        u32x4 bnext[4];
        if (more) {
            na0 = *(const f32x4*)(Ap + k0 + 32);
            na1 = *(const f32x4*)(Ap + k0 + 36);
            #pragma unroll
            for (int j = 0; j < 4; j++)
                bnext[j] = *(const u32x4*)(Bq + j * 16 * 512 + k0 + 32);
        }
        short8 af[4];
        #pragma unroll
        for (int i = 0; i < 4; i++)
            af[i] = *(const short8*)&As[buf][(i * 16 + lm) * 40 + q * 8];
        #pragma unroll
        for (int i = 0; i < 4; i++)
            #pragma unroll
            for (int j = 0; j < 4; j++)
                acc[i][j] = __builtin_amdgcn_mfma_f32_16x16x32_bf16(af[i], *(const short8*)&bcur[j], acc[i][j], 0, 0, 0);
        if (more) {
            u32x4 ap;
            ap.x = (unsigned int)f2bf(na0.x) | ((unsigned int)f2bf(na0.y) << 16);
            ap.y = (unsigned int)f2bf(na0.z) | ((unsigned int)f2bf(na0.w) << 16);
            ap.z = (unsigned int)f2bf(na1.x) | ((unsigned int)f2bf(na1.y) << 16);
            ap.w = (unsigned int)f2bf(na1.z) | ((unsigned int)f2bf(na1.w) << 16);
            *(u32x4*)&As[buf ^ 1][ra * 40 + kc] = ap;
            __syncthreads();
            #pragma unroll
            for (int j = 0; j < 4; j++) bcur[j] = bnext[j];
        }
        buf ^= 1;
    }

    #pragma unroll
    for (int i = 0; i < 4; i++) {
        #pragma unroll
        for (int r = 0; r < 4; r++) {
            int m = m0 + i * 16 + q * 4 + r;
            if (m < M) {
                float d = dinv[m];
                #pragma unroll
                for (int j = 0; j < 4; j++) {
                    int n = wn + j * 16 + lm;
                    xs[(size_t)m * 256 + n] = f2bf(acc[i][j][r] * d);
                }
            }
        }
    }
}

// ---------------- FUSED layer-1 aggregate + layer-2 GEMM ----------------
// Block = 16 columns (4 waves x 4 sequential columns). Per column: gather xs rows
// (lane l: features (l&31)*8..+7 via uint4; lanes 0-31/32-63 even/odd edges),
// fold, +self, *dinv, +b1, ReLU, pack bf16 -> LDS hs[16][264] (same pack as old h).
// Then one barrier; waves 0-2 run the 16x48 MFMA (h @ W2), B direct from L2-hot w2t,
// and write t2p = bf16(acc * dinv[m]) -- bit-identical to the old gemm2 path.
// h buffer, gemm2 kernel, and its 100 MB round-trip are eliminated.

__global__ __launch_bounds__(256) void spmm1f_kernel(const unsigned short* __restrict__ xs,
                                                     const int* __restrict__ colptr,
                                                     const int* __restrict__ eidx,
                                                     const float* __restrict__ dinv,
                                                     const float* __restrict__ b1,
                                                     const unsigned short* __restrict__ w2t,
                                                     unsigned short* __restrict__ t2p, int Nn) {
    __shared__ unsigned short hs[16 * 264];
    int wid = threadIdx.x >> 6, lane = threadIdx.x & 63;
    int base = blockIdx.x * 16;
    int half = lane >> 5;
    int fl = lane & 31;
    int lm = lane & 15, q = lane >> 4;
    const uint4* xb = (const uint4*)xs;

    #pragma unroll 1
    for (int tcol = 0; tcol < 4; tcol++) {
        int cl = wid * 4 + tcol;
        int c = base + cl;
        uint4 p;
        if (c < Nn) {
            uint4 sv = xb[(size_t)((unsigned)c * 32u + fl)];

            float a0 = 0.f, a1 = 0.f, a2 = 0.f, a3 = 0.f;
            float a4 = 0.f, a5 = 0.f, a6 = 0.f, a7 = 0.f;

            int j = colptr[c], jend = colptr[c + 1];

            for (; j + 8 <= jend; j += 8) {
                int r0 = eidx[j     + half];
                int r1 = eidx[j + 2 + half];
                int r2 = eidx[j + 4 + half];
                int r3 = eidx[j + 6 + half];
                uint4 v0 = xb[(size_t)((unsigned)r0 * 32u + fl)];
                uint4 v1 = xb[(size_t)((unsigned)r1 * 32u + fl)];
                uint4 v2 = xb[(size_t)((unsigned)r2 * 32u + fl)];
                uint4 v3 = xb[(size_t)((unsigned)r3 * 32u + fl)];
                a0 += (blo(v0.x) + blo(v1.x)) + (blo(v2.x) + blo(v3.x));
                a1 += (bhi(v0.x) + bhi(v1.x)) + (bhi(v2.x) + bhi(v3.x));
                a2 += (blo(v0.y) + blo(v1.y)) + (blo(v2.y) + blo(v3.y));
                a3 += (bhi(v0.y) + bhi(v1.y)) + (bhi(v2.y) + bhi(v3.y));
                a4 += (blo(v0.z) + blo(v1.z)) + (blo(v2.z) + blo(v3.z));
                a5 += (bhi(v0.z) + bhi(v1.z)) + (bhi(v2.z) + bhi(v3.z));
                a6 += (blo(v0.w) + blo(v1.w)) + (blo(v2.w) + blo(v3.w));
                a7 += (bhi(v0.w) + bhi(v1.w)) + (bhi(v2.w) + bhi(v3.w));
            }
            for (; j < jend; j += 2) {
                int e = j + half;
                bool ok = e < jend;
                int r = eidx[ok ? e : (jend - 1)];
                float m = ok ? 1.f : 0.f;
                uint4 v = xb[(size_t)((unsigned)r * 32u + fl)];
                a0 = fmaf(m, blo(v.x), a0);
                a1 = fmaf(m, bhi(v.x), a1);
                a2 = fmaf(m, blo(v.y), a2);
                a3 = fmaf(m, bhi(v.y), a3);
                a4 = fmaf(m, blo(v.z), a4);
                a5 = fmaf(m, bhi(v.z), a5);
                a6 = fmaf(m, blo(v.w), a6);
                a7 = fmaf(m, bhi(v.w), a7);
            }

            a0 += __shfl_xor(a0, 32);
            a1 += __shfl_xor(a1, 32);
            a2 += __shfl_xor(a2, 32);
            a3 += __shfl_xor(a3, 32);
            a4 += __shfl_xor(a4, 32);
            a5 += __shfl_xor(a5, 32);
            a6 += __shfl_xor(a6, 32);
            a7 += __shfl_xor(a7, 32);

            a0 += blo(sv.x); a1 += bhi(sv.x);
            a2 += blo(sv.y); a3 += bhi(sv.y);
            a4 += blo(sv.z); a5 += bhi(sv.z);
            a6 += blo(sv.w); a7 += bhi(sv.w);

            float d = dinv[c];
            float4 bb0 = ((const float4*)b1)[fl * 2];
            float4 bb1 = ((const float4*)b1)[fl * 2 + 1];
            float f0 = fmaxf(a0 * d + bb0.x, 0.f);
            float f1 = fmaxf(a1 * d + bb0.y, 0.f);
            float f2 = fmaxf(a2 * d + bb0.z, 0.f);
            float f3 = fmaxf(a3 * d + bb0.w, 0.f);
            float f4 = fmaxf(a4 * d + bb1.x, 0.f);
            float f5 = fmaxf(a5 * d + bb1.y, 0.f);
            float f6 = fmaxf(a6 * d + bb1.z, 0.f);
            float f7 = fmaxf(a7 * d + bb1.w, 0.f);
            p.x = (unsigned int)f2bf(f0) | ((unsigned int)f2bf(f1) << 16);
            p.y = (unsigned int)f2bf(f2) | ((unsigned int)f2bf(f3) << 16);
            p.z = (unsigned int)f2bf(f4) | ((unsigned int)f2bf(f5) << 16);
            p.w = (unsigned int)f2bf(f6) | ((unsigned int)f2bf(f7) << 16);
        } else {
            p.x = 0u; p.y = 0u; p.z = 0u; p.w = 0u;
        }
        if (lane < 32)
            *(uint4*)&hs[cl * 264 + fl * 8] = p;
    }

    __syncthreads();

    // MFMA tail: 16 rows (this block's columns) x 48 output cols, K=256.
    if (wid < 3) {
        int jf = wid;
        const unsigned short* Bq2 = w2t + (size_t)(jf * 16 + lm) * 256 + q * 8;
        f32x4 acc = {0.f, 0.f, 0.f, 0.f};
        #pragma unroll
        for (int k0 = 0; k0 < 256; k0 += 32) {
            short8 af = *(const short8*)&hs[lm * 264 + k0 + q * 8];
            short8 bf = *(const short8*)(Bq2 + k0);
            acc = __builtin_amdgcn_mfma_f32_16x16x32_bf16(af, bf, acc, 0, 0, 0);
        }
        #pragma unroll
        for (int r = 0; r < 4; r++) {
            int m = base + q * 4 + r;
            if (m < Nn) {
                float d = dinv[m];
                t2p[(size_t)m * 64 + jf * 16 + lm] = f2bf(acc[r] * d);
            }
        }
    }
}

// ---------------- layer 2 aggregate + bias + log_softmax ----------------
// t2p rows 128B aligned. Lane l: edge slot g=l>>3 (8 slots), feature block fl=l&7
// (fl<5 valid; 5-7 clamp). One dwordx4 instr = 8 edge rows; 16 edges in flight.

__global__ __launch_bounds__(256) void spmm2_kernel(const unsigned short* __restrict__ t2p,
                                                    const int* __restrict__ colptr,
                                                    const int* __restrict__ eidx,
                                                    const float* __restrict__ dinv,
                                                    const float* __restrict__ b2,
                                                    float* __restrict__ out, int Nn) {
    int wid = threadIdx.x >> 6, lane = threadIdx.x & 63;
    int c = blockIdx.x * 4 + wid;
    if (c >= Nn) return;
    int g = lane >> 3;
    int fl = lane & 7;
    int flc = (fl < 5) ? fl : 4;
    const u32x4* tb = (const u32x4*)t2p;

    u32x4 sv = tb[(size_t)((unsigned)c * 8u + flc)];

    float a0 = 0.f, a1 = 0.f, a2 = 0.f, a3 = 0.f;
    float a4 = 0.f, a5 = 0.f, a6 = 0.f, a7 = 0.f;
    int j = colptr[c], jend = colptr[c + 1];

    for (; j + 16 <= jend; j += 16) {
        int r0 = eidx[j     + g];
        int r1 = eidx[j + 8 + g];
        u32x4 v0 = tb[(size_t)((unsigned)r0 * 8u + flc)];
        u32x4 v1 = tb[(size_t)((unsigned)r1 * 8u + flc)];
        a0 += blo(v0.x) + blo(v1.x);
        a1 += bhi(v0.x) + bhi(v1.x);
        a2 += blo(v0.y) + blo(v1.y);
        a3 += bhi(v0.y) + bhi(v1.y);
        a4 += blo(v0.z) + blo(v1.z);
        a5 += bhi(v0.z) + bhi(v1.z);
        a6 += blo(v0.w) + blo(v1.w);
        a7 += bhi(v0.w) + bhi(v1.w);
    }
    for (; j < jend; j += 8) {
        int e = j + g;
        bool ok = e < jend;
        int r = eidx[ok ? e : (jend - 1)];
        float m = ok ? 1.f : 0.f;
        u32x4 v = tb[(size_t)((unsigned)r * 8u + flc)];
        a0 = fmaf(m, blo(v.x), a0);
        a1 = fmaf(m, bhi(v.x), a1);
        a2 = fmaf(m, blo(v.y), a2);
        a3 = fmaf(m, bhi(v.y), a3);
        a4 = fmaf(m, blo(v.z), a4);
        a5 = fmaf(m, bhi(v.z), a5);
        a6 = fmaf(m, blo(v.w), a6);
        a7 = fmaf(m, bhi(v.w), a7);
    }

    #pragma unroll
    for (int o = 8; o <= 32; o <<= 1) {
        a0 += __shfl_xor(a0, o);
        a1 += __shfl_xor(a1, o);
        a2 += __shfl_xor(a2, o);
        a3 += __shfl_xor(a3, o);
        a4 += __shfl_xor(a4, o);
        a5 += __shfl_xor(a5, o);
        a6 += __shfl_xor(a6, o);
        a7 += __shfl_xor(a7, o);
    }

    a0 += blo(sv.x); a1 += bhi(sv.x);
    a2 += blo(sv.y); a3 += bhi(sv.y);
    a4 += blo(sv.z); a5 += bhi(sv.z);
    a6 += blo(sv.w); a7 += bhi(sv.w);

    float d = dinv[c];
    bool valid = fl < 5;
    float4 bb0 = {0.f, 0.f, 0.f, 0.f}, bb1 = {0.f, 0.f, 0.f, 0.f};
    if (valid) {
        bb0 = ((const float4*)b2)[fl * 2];
        bb1 = ((const float4*)b2)[fl * 2 + 1];
    }
    float v0 = valid ? (a0 * d + bb0.x) : -INFINITY;
    float v1 = valid ? (a1 * d + bb0.y) : -INFINITY;
    float v2 = valid ? (a2 * d + bb0.z) : -INFINITY;
    float v3 = valid ? (a3 * d + bb0.w) : -INFINITY;
    float v4 = valid ? (a4 * d + bb1.x) : -INFINITY;
    float v5 = valid ? (a5 * d + bb1.y) : -INFINITY;
    float v6 = valid ? (a6 * d + bb1.z) : -INFINITY;
    float v7 = valid ? (a7 * d + bb1.w) : -INFINITY;

    float mx = fmaxf(fmaxf(fmaxf(v0, v1), fmaxf(v2, v3)),
                     fmaxf(fmaxf(v4, v5), fmaxf(v6, v7)));
    #pragma unroll
    for (int o = 1; o <= 4; o <<= 1) { float zz = __shfl_xor(mx, o); mx = fmaxf(mx, zz); }
    float ex = valid ? (expf(v0 - mx) + expf(v1 - mx) + expf(v2 - mx) + expf(v3 - mx)
                      + expf(v4 - mx) + expf(v5 - mx) + expf(v6 - mx) + expf(v7 - mx)) : 0.f;
    #pragma unroll
    for (int o = 1; o <= 4; o <<= 1) ex += __shfl_xor(ex, o);
    float ls = logf(ex);

    if (lane < 5) {
        float4 oa, ob;
        oa.x = v0 - mx - ls; oa.y = v1 - mx - ls;
        oa.z = v2 - mx - ls; oa.w = v3 - mx - ls;
        ob.x = v4 - mx - ls; ob.y = v5 - mx - ls;
        ob.z = v6 - mx - ls; ob.w = v7 - mx - ls;
        *(float4*)(out + (size_t)c * 40 + fl * 8)     = oa;
        *(float4*)(out + (size_t)c * 40 + fl * 8 + 4) = ob;
    }
}

// ---------------- launcher ----------------

extern "C" void kernel_launch(void* const* d_in, const int* in_sizes, int n_in,
                              void* d_out, int out_size, void* d_ws, size_t ws_size,
                              hipStream_t stream) {
    const float* x  = (const float*)d_in[0];
    const int*   ei = (const int*)d_in[1];
    const float* W1 = (const float*)d_in[2];
    const float* b1 = (const float*)d_in[3];
    const float* W2 = (const float*)d_in[4];
    const float* b2 = (const float*)d_in[5];
    float* out = (float*)d_out;

    int N = in_sizes[0] / 512;   // 100000
    int E = in_sizes[1] / 2;     // 3200000

    char* p = (char*)d_ws;
    auto carve = [&](size_t bytes) -> char* {
        char* q = p;
        p += (bytes + 1023) & ~(size_t)1023;
        return q;
    };
    float* dinv   = (float*)carve((size_t)N * 4);
    int*   cnt    = (int*)carve((size_t)N * 4);
    int*   colptr = (int*)carve(((size_t)N + 1) * 4);
    int*   fillc  = (int*)carve((size_t)N * 4);
    int*   bsum   = (int*)carve(1024 * 4);
    int*   eidx   = (int*)carve((size_t)E * 4);
    unsigned short* w1t = (unsigned short*)carve((size_t)256 * 512 * 2);
    unsigned short* w2t = (unsigned short*)carve((size_t)64 * 256 * 2);
    unsigned short* xs  = (unsigned short*)carve((size_t)N * 256 * 2);
    unsigned short* t2p = (unsigned short*)carve((size_t)N * 64 * 2);

    hipMemsetAsync(cnt,   0, (size_t)N * 4, stream);
    hipMemsetAsync(fillc, 0, (size_t)N * 4, stream);

    int eb = (E + 255) / 256;
    int nb = (N + 511) / 512;

    count_kernel<<<eb, 256, 0, stream>>>(ei, cnt, E);
    scanA_kernel<<<nb, 256, 0, stream>>>(cnt, dinv, colptr, bsum, N);
    scanB_kernel<<<1, 256, 0, stream>>>(bsum, nb);
    scanC_kernel<<<nb, 256, 0, stream>>>(colptr, bsum, N, E);
    fill_kernel<<<eb, 256, 0, stream>>>(ei, colptr, fillc, eidx, E);
    prep_w_kernel<<<576, 256, 0, stream>>>(W1, W2, w1t, w2t);

    int mb = (N + 63) / 64;
    gemm1_kernel<<<mb, 256, 0, stream>>>(x, w1t, dinv, xs, N);
    spmm1f_kernel<<<(N + 15) / 16, 256, 0, stream>>>(xs, colptr, eidx, dinv, b1, w2t, t2p, N);
    spmm2_kernel<<<(N + 3) / 4, 256, 0, stream>>>(t2p, colptr, eidx, dinv, b2, out, N);
}